// Round 1
// baseline (74.438 us; speedup 1.0000x reference)
//
#include <hip/hip_runtime.h>
#include <math.h>

namespace {

constexpr int L      = 3750;
constexpr int NPAIR  = L / 2;     // 1875 float2 per row
constexpr int BLK    = 256;
constexpr int CH     = 15;        // scan chunk per thread
constexpr int NCHUNK = L / CH;    // 250 active scan threads
constexpr float EPS  = 1e-5f;

__global__ __launch_bounds__(BLK)
void preproc_kernel(const float* __restrict__ in, float* __restrict__ out) {
    __shared__ float sy[L];       // row -> y -> z (in place)
    __shared__ float sp[L + 1];   // prefix sums (reused for both pools)
    __shared__ float sred[4];     // per-wave partials

    const int tid  = threadIdx.x;
    const int lane = tid & 63;
    const int wave = tid >> 6;
    const size_t rowoff = (size_t)blockIdx.x * (size_t)L;
    const float* rin  = in  + rowoff;
    float*       rout = out + rowoff;

    // ---- 1. load row into LDS (float2 coalesced), accumulate sum ----
    float s = 0.f;
    {
        const float2* rin2 = reinterpret_cast<const float2*>(rin);
        float2* sy2 = reinterpret_cast<float2*>(sy);
        for (int i = tid; i < NPAIR; i += BLK) {
            float2 v = rin2[i];
            sy2[i] = v;
            s += v.x + v.y;
        }
    }
    #pragma unroll
    for (int d = 1; d < 64; d <<= 1) s += __shfl_xor(s, d, 64);
    if (lane == 0) sred[wave] = s;
    __syncthreads();
    const float mean = (sred[0] + sred[1] + sred[2] + sred[3]) * (1.f / (float)L);
    __syncthreads();  // sred reused below

    // ---- 2. unbiased variance (two-pass, ddof=1) ----
    float s2 = 0.f;
    for (int i = tid; i < L; i += BLK) {
        float d = sy[i] - mean;
        s2 += d * d;
    }
    #pragma unroll
    for (int d = 1; d < 64; d <<= 1) s2 += __shfl_xor(s2, d, 64);
    if (lane == 0) sred[wave] = s2;
    __syncthreads();
    const float var  = (sred[0] + sred[1] + sred[2] + sred[3]) * (1.f / (float)(L - 1));
    const float zinv = 1.f / (sqrtf(var) + EPS);

    // ---- 3. z-norm in place ----
    for (int i = tid; i < L; i += BLK) {
        sy[i] = (sy[i] - mean) * zinv;
    }
    __syncthreads();   // sy final + sred free for scan

    // ---- 4. prefix sum of y -> sp ----
    {
        float loc[CH];
        float ct = 0.f;
        if (tid < NCHUNK) {
            const int base = tid * CH;
            #pragma unroll
            for (int j = 0; j < CH; ++j) { loc[j] = ct; ct += sy[base + j]; }
        }
        const float v = (tid < NCHUNK) ? ct : 0.f;
        float incl = v;
        #pragma unroll
        for (int d = 1; d < 64; d <<= 1) {
            float u = __shfl_up(incl, (unsigned)d, 64);
            if (lane >= d) incl += u;
        }
        if (lane == 63) sred[wave] = incl;
        __syncthreads();
        float woff = 0.f;
        for (int w = 0; w < wave; ++w) woff += sred[w];
        const float excl = woff + incl - v;
        if (tid < NCHUNK) {
            const int base = tid * CH;
            #pragma unroll
            for (int j = 0; j < CH; ++j) sp[base + j] = excl + loc[j];
            if (tid == NCHUNK - 1) sp[L] = excl + ct;
        }
        __syncthreads();
    }

    // ---- 5. subtract moving average (K=251, zero-pad, count_include_pad) ----
    for (int i = tid; i < L; i += BLK) {
        const int lo = (i - 125 > 0) ? (i - 125) : 0;
        const int hi = (i + 126 < L) ? (i + 126) : L;
        sy[i] -= (sp[hi] - sp[lo]) * (1.f / 251.f);
    }
    __syncthreads();   // sp reads done; safe to rebuild

    // ---- 6. prefix sum of z^2 -> sp ----
    {
        float loc[CH];
        float ct = 0.f;
        if (tid < NCHUNK) {
            const int base = tid * CH;
            #pragma unroll
            for (int j = 0; j < CH; ++j) {
                loc[j] = ct;
                const float q = sy[base + j];
                ct += q * q;
            }
        }
        const float v = (tid < NCHUNK) ? ct : 0.f;
        float incl = v;
        #pragma unroll
        for (int d = 1; d < 64; d <<= 1) {
            float u = __shfl_up(incl, (unsigned)d, 64);
            if (lane >= d) incl += u;
        }
        if (lane == 63) sred[wave] = incl;
        __syncthreads();
        float woff = 0.f;
        for (int w = 0; w < wave; ++w) woff += sred[w];
        const float excl = woff + incl - v;
        if (tid < NCHUNK) {
            const int base = tid * CH;
            #pragma unroll
            for (int j = 0; j < CH; ++j) sp[base + j] = excl + loc[j];
            if (tid == NCHUNK - 1) sp[L] = excl + ct;
        }
        __syncthreads();
    }

    // ---- 7. divide by moving std (K=501) and store (float2 coalesced) ----
    for (int i = tid; i < NPAIR; i += BLK) {
        const int i0 = 2 * i;
        float2 r;
        {
            const int lo = (i0 - 250 > 0) ? (i0 - 250) : 0;
            const int hi = (i0 + 251 < L) ? (i0 + 251) : L;
            float mv = (sp[hi] - sp[lo]) * (1.f / 501.f);
            mv = fmaxf(mv, 0.f);
            r.x = sy[i0] / (sqrtf(mv) + EPS);
        }
        {
            const int i1 = i0 + 1;
            const int lo = (i1 - 250 > 0) ? (i1 - 250) : 0;
            const int hi = (i1 + 251 < L) ? (i1 + 251) : L;
            float mv = (sp[hi] - sp[lo]) * (1.f / 501.f);
            mv = fmaxf(mv, 0.f);
            r.y = sy[i1] / (sqrtf(mv) + EPS);
        }
        reinterpret_cast<float2*>(rout)[i] = r;
    }
}

}  // namespace

extern "C" void kernel_launch(void* const* d_in, const int* in_sizes, int n_in,
                              void* d_out, int out_size, void* d_ws, size_t ws_size,
                              hipStream_t stream) {
    const float* x = (const float*)d_in[0];
    float* out = (float*)d_out;
    const int rows = in_sizes[0] / L;   // 8192
    preproc_kernel<<<rows, BLK, 0, stream>>>(x, out);
}

// Round 2
// 54.274 us; speedup vs baseline: 1.3715x; 1.3715x over previous
//
#include <hip/hip_runtime.h>
#include <math.h>

namespace {

constexpr int L      = 3750;
constexpr int NPAIR  = L / 2;     // 1875 float2 per row
constexpr int BLK    = 256;
constexpr int CH     = 15;        // scan chunk per thread
constexpr int NCHUNK = L / CH;    // 250 active scan threads
constexpr float EPS  = 1e-5f;

__device__ __forceinline__ float frcp(float x)  { return __builtin_amdgcn_rcpf(x); }
__device__ __forceinline__ float fsqrt(float x) { return __builtin_amdgcn_sqrtf(x); }

__global__ __launch_bounds__(BLK)
void preproc_kernel(const float* __restrict__ in, float* __restrict__ out) {
    __shared__ float sy[L];       // raw y -> t (in place, chunk-owned)
    __shared__ float sp[L + 1];   // prefix of y, then prefix of t^2
    __shared__ float sred[8];     // wave partials: [0:4)=y, [4:8)=y^2

    const int tid  = threadIdx.x;
    const int lane = tid & 63;
    const int wave = tid >> 6;
    const size_t rowoff = (size_t)blockIdx.x * (size_t)L;
    const float* rin  = in  + rowoff;
    float*       rout = out + rowoff;

    // ---- 1. load row into LDS (float2 coalesced) ----
    {
        const float2* rin2 = reinterpret_cast<const float2*>(rin);
        float2* sy2 = reinterpret_cast<float2*>(sy);
        for (int i = tid; i < NPAIR; i += BLK) sy2[i] = rin2[i];
    }
    __syncthreads();

    // ---- 2. scan A: prefix of raw y -> sp; totals of y, y^2 -> mean/var ----
    float mean, zinv;
    {
        float loc[CH];
        float cy = 0.f, cy2 = 0.f;
        if (tid < NCHUNK) {
            const int base = tid * CH;
            #pragma unroll
            for (int j = 0; j < CH; ++j) {
                loc[j] = cy;
                const float v = sy[base + j];
                cy  += v;
                cy2 += v * v;
            }
        }
        float iy  = (tid < NCHUNK) ? cy  : 0.f;
        float iy2 = (tid < NCHUNK) ? cy2 : 0.f;
        const float vy = iy;
        #pragma unroll
        for (int d = 1; d < 64; d <<= 1) {
            const float u  = __shfl_up(iy,  (unsigned)d, 64);
            const float u2 = __shfl_up(iy2, (unsigned)d, 64);
            if (lane >= d) { iy += u; iy2 += u2; }
        }
        if (lane == 63) { sred[wave] = iy; sred[4 + wave] = iy2; }
        __syncthreads();
        float woff = 0.f;
        for (int w = 0; w < wave; ++w) woff += sred[w];
        const float totY  = sred[0] + sred[1] + sred[2] + sred[3];
        const float totY2 = sred[4] + sred[5] + sred[6] + sred[7];
        mean = totY * (1.f / (float)L);
        const float var = (totY2 - totY * mean) * (1.f / (float)(L - 1));
        zinv = frcp(fsqrt(var) + EPS);   // 1/(std+eps)
        const float excl = woff + iy - vy;
        if (tid < NCHUNK) {
            const int base = tid * CH;
            #pragma unroll
            for (int j = 0; j < CH; ++j) sp[base + j] = excl + loc[j];
            if (tid == NCHUNK - 1) sp[L] = excl + cy;
        }
        __syncthreads();   // sp(y-prefix) ready; sred consumed
    }

    // ---- 3. pass B: t = z - MA (chunk-owned, in place), scan of t^2 -> sp ----
    {
        const float zinv251 = zinv * (1.f / 251.f);
        float loc[CH];
        float ct = 0.f;
        if (tid < NCHUNK) {
            const int base = tid * CH;
            #pragma unroll
            for (int j = 0; j < CH; ++j) {
                const int i  = base + j;
                const int lo = (i > 125) ? (i - 125) : 0;
                const int hi = (i + 126 < L) ? (i + 126) : L;
                // window-sum of z from raw-y prefix:  (P[hi]-P[lo]-(hi-lo)*mean)*zinv
                const float winY = sp[hi] - sp[lo] - (float)(hi - lo) * mean;
                const float z    = (sy[i] - mean) * zinv;
                const float t    = z - winY * zinv251;
                sy[i]  = t;          // only owner thread reads sy in this pass
                loc[j] = ct;
                ct += t * t;
            }
        }
        const float vt = (tid < NCHUNK) ? ct : 0.f;
        float it = vt;
        #pragma unroll
        for (int d = 1; d < 64; d <<= 1) {
            const float u = __shfl_up(it, (unsigned)d, 64);
            if (lane >= d) it += u;
        }
        if (lane == 63) sred[wave] = it;
        __syncthreads();   // also guarantees all sp reads above are done
        float woff = 0.f;
        for (int w = 0; w < wave; ++w) woff += sred[w];
        const float excl = woff + it - vt;
        if (tid < NCHUNK) {
            const int base = tid * CH;
            #pragma unroll
            for (int j = 0; j < CH; ++j) sp[base + j] = excl + loc[j];
            if (tid == NCHUNK - 1) sp[L] = excl + ct;
        }
        __syncthreads();   // sp(t^2-prefix) + sy(t) ready
    }

    // ---- 4. divide by moving std (K=501) and store (float2 coalesced) ----
    {
        const float inv501 = 1.f / 501.f;
        const float2* st2 = reinterpret_cast<const float2*>(sy);
        for (int i = tid; i < NPAIR; i += BLK) {
            const int i0 = 2 * i;
            const float2 tv = st2[i];
            float2 r;
            {
                const int lo = (i0 > 250) ? (i0 - 250) : 0;
                const int hi = (i0 + 251 < L) ? (i0 + 251) : L;
                float mv = (sp[hi] - sp[lo]) * inv501;
                mv = fmaxf(mv, 0.f);
                r.x = tv.x * frcp(fsqrt(mv) + EPS);
            }
            {
                const int i1 = i0 + 1;
                const int lo = (i1 > 250) ? (i1 - 250) : 0;
                const int hi = (i1 + 251 < L) ? (i1 + 251) : L;
                float mv = (sp[hi] - sp[lo]) * inv501;
                mv = fmaxf(mv, 0.f);
                r.y = tv.y * frcp(fsqrt(mv) + EPS);
            }
            reinterpret_cast<float2*>(rout)[i] = r;
        }
    }
}

}  // namespace

extern "C" void kernel_launch(void* const* d_in, const int* in_sizes, int n_in,
                              void* d_out, int out_size, void* d_ws, size_t ws_size,
                              hipStream_t stream) {
    const float* x = (const float*)d_in[0];
    float* out = (float*)d_out;
    const int rows = in_sizes[0] / L;   // 8192
    preproc_kernel<<<rows, BLK, 0, stream>>>(x, out);
}

// Round 3
// 52.748 us; speedup vs baseline: 1.4112x; 1.0289x over previous
//
#include <hip/hip_runtime.h>
#include <math.h>

namespace {

constexpr int L      = 3750;
constexpr int NPAIR  = L / 2;     // 1875 float2 per row
constexpr int BLK    = 256;
constexpr int CH     = 15;        // chunk per thread (registers)
constexpr int NCHUNK = L / CH;    // 250 active chunk threads
constexpr float EPS  = 1e-5f;

__device__ __forceinline__ float frcp(float x)  { return __builtin_amdgcn_rcpf(x); }
__device__ __forceinline__ float fsqrt(float x) { return __builtin_amdgcn_sqrtf(x); }

__global__ __launch_bounds__(BLK, 8)
void preproc_kernel(const float* __restrict__ in, float* __restrict__ out) {
    // ONE row-sized LDS array, reused: staging -> y-prefix -> t^2-prefix -> result
    __shared__ __align__(16) float sp[L + 1];
    __shared__ float sred[8];     // wave partials: [0:4) sum, [4:8) sum of squares

    const int tid  = threadIdx.x;
    const int lane = tid & 63;
    const int wave = tid >> 6;
    const size_t rowoff = (size_t)blockIdx.x * (size_t)L;
    const float* rin  = in  + rowoff;
    float*       rout = out + rowoff;

    // ---- 1. coalesced load of the row into sp[0..L) ----
    {
        const float2* rin2 = reinterpret_cast<const float2*>(rin);
        float2* sp2 = reinterpret_cast<float2*>(sp);
        for (int i = tid; i < NPAIR; i += BLK) sp2[i] = rin2[i];
    }
    __syncthreads();

    // ---- 2. chunk -> registers; wave scan of (sum, sumsq) ----
    float y[CH];
    float cy = 0.f, cy2 = 0.f;
    const int base = tid * CH;
    if (tid < NCHUNK) {
        #pragma unroll
        for (int j = 0; j < CH; ++j) {
            const float v = sp[base + j];
            y[j] = v;
            cy  += v;
            cy2 += v * v;
        }
    }
    float iy = cy, iy2 = cy2;
    #pragma unroll
    for (int d = 1; d < 64; d <<= 1) {
        const float u  = __shfl_up(iy,  (unsigned)d, 64);
        const float u2 = __shfl_up(iy2, (unsigned)d, 64);
        if (lane >= d) { iy += u; iy2 += u2; }
    }
    if (lane == 63) { sred[wave] = iy; sred[4 + wave] = iy2; }
    __syncthreads();                      // also: all sp reads done -> safe to overwrite
    float woff = 0.f;
    for (int w = 0; w < wave; ++w) woff += sred[w];
    const float totY  = sred[0] + sred[1] + sred[2] + sred[3];
    const float totY2 = sred[4] + sred[5] + sred[6] + sred[7];
    const float mean  = totY * (1.f / (float)L);
    const float var   = (totY2 - totY * mean) * (1.f / (float)(L - 1));
    const float zinv  = frcp(fsqrt(var) + EPS);     // 1/(std+eps)

    // ---- 3. write exclusive y-prefix into sp (recompute running sum) ----
    {
        float run = woff + iy - cy;       // exclusive prefix at chunk start
        if (tid < NCHUNK) {
            #pragma unroll
            for (int j = 0; j < CH; ++j) { sp[base + j] = run; run += y[j]; }
            if (tid == NCHUNK - 1) sp[L] = run;
        }
    }
    __syncthreads();                      // y-prefix ready; sred(A) reads all done above

    // ---- 4. pass B: t = z - MA(z) via affine prefix identity; scan t^2 ----
    float ct = 0.f;
    {
        const float zinv251 = zinv * (1.f / 251.f);
        if (tid < NCHUNK) {
            #pragma unroll
            for (int j = 0; j < CH; ++j) {
                const int i  = base + j;
                const int lo = (i > 125) ? (i - 125) : 0;
                const int hi = (i + 126 < L) ? (i + 126) : L;
                // sum_{[lo,hi)} z = (P_y[hi]-P_y[lo]-(hi-lo)*mean)*zinv
                const float winY = sp[hi] - sp[lo] - (float)(hi - lo) * mean;
                const float z    = (y[j] - mean) * zinv;
                const float t    = z - winY * zinv251;
                y[j] = t;
                ct  += t * t;
            }
        }
    }
    float it = ct;
    #pragma unroll
    for (int d = 1; d < 64; d <<= 1) {
        const float u = __shfl_up(it, (unsigned)d, 64);
        if (lane >= d) it += u;
    }
    if (lane == 63) sred[wave] = it;      // safe: last sred(A) read was before barrier 3
    __syncthreads();                      // window reads done -> safe to overwrite sp
    float woff2 = 0.f;
    for (int w = 0; w < wave; ++w) woff2 += sred[w];

    // ---- 5. write exclusive t^2-prefix into sp ----
    {
        float run = woff2 + it - ct;
        if (tid < NCHUNK) {
            #pragma unroll
            for (int j = 0; j < CH; ++j) { sp[base + j] = run; run += y[j] * y[j]; }
            if (tid == NCHUNK - 1) sp[L] = run;
        }
    }
    __syncthreads();                      // t^2-prefix ready

    // ---- 6. epilogue: r = t / (sqrt(mv)+eps), in registers ----
    {
        const float inv501 = 1.f / 501.f;
        if (tid < NCHUNK) {
            #pragma unroll
            for (int j = 0; j < CH; ++j) {
                const int i  = base + j;
                const int lo = (i > 250) ? (i - 250) : 0;
                const int hi = (i + 251 < L) ? (i + 251) : L;
                float mv = (sp[hi] - sp[lo]) * inv501;
                mv = fmaxf(mv, 0.f);
                y[j] = y[j] * frcp(fsqrt(mv) + EPS);
            }
        }
    }
    __syncthreads();                      // all window reads done -> safe to overwrite

    // ---- 7. bounce r through sp (chunk layout == linear) and store coalesced ----
    if (tid < NCHUNK) {
        #pragma unroll
        for (int j = 0; j < CH; ++j) sp[base + j] = y[j];
    }
    __syncthreads();
    {
        const float2* sp2 = reinterpret_cast<const float2*>(sp);
        float2* rout2 = reinterpret_cast<float2*>(rout);
        for (int i = tid; i < NPAIR; i += BLK) rout2[i] = sp2[i];
    }
}

}  // namespace

extern "C" void kernel_launch(void* const* d_in, const int* in_sizes, int n_in,
                              void* d_out, int out_size, void* d_ws, size_t ws_size,
                              hipStream_t stream) {
    const float* x = (const float*)d_in[0];
    float* out = (float*)d_out;
    const int rows = in_sizes[0] / L;   // 8192
    preproc_kernel<<<rows, BLK, 0, stream>>>(x, out);
}